// Round 3
// baseline (955.120 us; speedup 1.0000x reference)
//
#include <hip/hip_runtime.h>
#include <hip/hip_bf16.h>

typedef __bf16 bf16x8 __attribute__((ext_vector_type(8)));
typedef float  f32x4  __attribute__((ext_vector_type(4)));

#define M_TOT 8192
#define N_TOT 4096
#define K_TOT 4096
#define NB    256     // number of 16-wide blocks along N or K
#define BM    128

// Mask storage-width flags, detected on-device each call (device global in our
// module; zero scratch usage).
__device__ int g_flags;

// ---------------------------------------------------------------------------
// Detect mask storage width: 1 B (bool/int8), 2 B (bf16/fp16), 4 B (int32/fp32).
//   bit0: byte==1 at odd index           -> width 1 (bool bytes 0/1; runs of 16
//         identical bytes guarantee odd-index hits)
//   bit1: byte in {0x3F,0x80,0x3C} at i%4==1 -> width 2
//         (bf16 1.0 = 80 3F ; fp16 1.0 = 00 3C)
//   neither                              -> width 4 (int32 01 00 00 00 has 0x01
//         only at i%4==0; fp32 1.0f = 00 00 80 3F has 0x00 at i%4==1)
// First 64 KB >= 1024 blocks at any width; P(no active block) <= 0.9^1024.
// ---------------------------------------------------------------------------
__global__ void bsl_detect(const unsigned char* __restrict__ mask) {
    __shared__ int sf[256];
    const int t = threadIdx.x;
    int f = 0;
    for (int i = t * 256; i < t * 256 + 256; ++i) {
        unsigned char b = mask[i];
        if (b) {
            if ((i & 1) && b == 1) f |= 1;
            if ((i & 3) == 1 && (b == 0x3F || b == 0x80 || b == 0x3C)) f |= 2;
        }
    }
    sf[t] = f;
    __syncthreads();
    if (t == 0) {
        int acc = 0;
        for (int i = 0; i < 256; ++i) acc |= sf[i];
        g_flags = acc;   // full overwrite every call
    }
}

// ---------------------------------------------------------------------------
// Block-sparse GEMM, fp32 in/out, bf16 MFMA compute.
// Workgroup = (128 m-rows) x (one 16-wide n-block). Per block: build active-k
// list in LDS (ballot compaction), then per PAIR of active k-blocks stage
// x (128x32) and W (16x32) tiles -- fp32 global loads converted to bf16 in
// registers, stored to LDS (row stride 40 shorts) -- then 4 waves x 2
// mfma_f32_16x16x32_bf16. Odd tail: x half duplicated, W half zeroed.
// Grid: blockIdx.x = n-block (fastest) so the 256 blocks sharing one 2 MB
// x m-tile are adjacent in dispatch -> x re-reads come from L2/LLC.
// ---------------------------------------------------------------------------
__global__ __launch_bounds__(256) void bsl_gemm(
        const float* __restrict__ x,
        const float* __restrict__ w,
        const float* __restrict__ bias,
        const unsigned char* __restrict__ mask,
        float* __restrict__ out) {
    __shared__ __hip_bfloat16 xs[BM][40];   // [row][k0(16) k1(16) pad(8)]
    __shared__ __hip_bfloat16 wls[16][40];
    __shared__ unsigned long long sball[4];
    __shared__ unsigned char klist[NB];

    const int j    = blockIdx.x;        // n-block (fastest-varying)
    const int m0   = blockIdx.y * BM;   // m-tile base
    const int t    = threadIdx.x;
    const int wave = t >> 6;
    const int lane = t & 63;
    const int q    = lane >> 4;         // quad
    const int rl   = lane & 15;

    // ---- build active-k list for this n-block ----
    const int flags = g_flags;
    unsigned int v;
    {
        const long long e = (long long)(j * 16) * K_TOT + (long long)t * 16;
        if (flags & 1)      v = mask[e];
        else if (flags & 2) v = ((const unsigned short*)mask)[e];
        else                v = ((const unsigned int*)mask)[e];
    }
    const bool active = (v != 0);
    const unsigned long long bal = __ballot(active);
    if (lane == 0) sball[wave] = bal;
    __syncthreads();
    int count = 0;
    #pragma unroll
    for (int wv = 0; wv < 4; ++wv) count += __popcll(sball[wv]);
    if (active) {
        int pos = __popcll(bal & ((1ull << lane) - 1));
        for (int wv = 0; wv < wave; ++wv) pos += __popcll(sball[wv]);
        klist[pos] = (unsigned char)t;
    }
    __syncthreads();

    // staging decomposition: thread t -> x row r, k-block-of-pair hh
    const int r  = t >> 1;    // 0..127
    const int hh = t & 1;     // 0: first k-block of pair, 1: second

    f32x4 acc0 = {0.f, 0.f, 0.f, 0.f};
    f32x4 acc1 = {0.f, 0.f, 0.f, 0.f};

    const int npairs = (count + 1) >> 1;
    for (int p = 0; p < npairs; ++p) {
        const int  kb1  = klist[2 * p];
        const bool has2 = (2 * p + 1) < count;
        const int  kb2  = has2 ? (int)klist[2 * p + 1] : kb1;
        const int  kb   = hh ? kb2 : kb1;

        // stage x: each thread loads 16 fp32 (one row-slice of one k-block),
        // converts to bf16, stores 32 B to LDS
        {
            const float4* src = (const float4*)(x + (long long)(m0 + r) * K_TOT + kb * 16);
            float4 f0 = src[0], f1 = src[1], f2 = src[2], f3 = src[3];
            union { __hip_bfloat16 h[16]; uint4 u[2]; } cv;
            const float ff[16] = {f0.x, f0.y, f0.z, f0.w, f1.x, f1.y, f1.z, f1.w,
                                  f2.x, f2.y, f2.z, f2.w, f3.x, f3.y, f3.z, f3.w};
            #pragma unroll
            for (int e = 0; e < 16; ++e) cv.h[e] = __float2bfloat16(ff[e]);
            *(uint4*)(&xs[r][hh * 16])     = cv.u[0];
            *(uint4*)(&xs[r][hh * 16 + 8]) = cv.u[1];
        }
        // stage W: threads 0..31, one row-slice of one k-block each
        if (t < 32) {
            const int rw = t >> 1;   // 0..15 (hh = t&1 as above)
            const bool valid = (hh == 0) || has2;
            float4 f0 = {0,0,0,0}, f1 = {0,0,0,0}, f2 = {0,0,0,0}, f3 = {0,0,0,0};
            if (valid) {
                const float4* wsrc = (const float4*)(w + (long long)(j * 16 + rw) * K_TOT + kb * 16);
                f0 = wsrc[0]; f1 = wsrc[1]; f2 = wsrc[2]; f3 = wsrc[3];
            }
            union { __hip_bfloat16 h[16]; uint4 u[2]; } cv;
            const float ff[16] = {f0.x, f0.y, f0.z, f0.w, f1.x, f1.y, f1.z, f1.w,
                                  f2.x, f2.y, f2.z, f2.w, f3.x, f3.y, f3.z, f3.w};
            #pragma unroll
            for (int e = 0; e < 16; ++e) cv.h[e] = __float2bfloat16(ff[e]);
            *(uint4*)(&wls[rw][hh * 16])     = cv.u[0];
            *(uint4*)(&wls[rw][hh * 16 + 8]) = cv.u[1];
        }
        __syncthreads();

        // fragments: A[m=lane&15][k=q*8+jj]; B[n=lane&15][k=q*8+jj] (W row-major [n][k])
        bf16x8 bf = *(const bf16x8*)(&wls[rl][q * 8]);
        bf16x8 a0 = *(const bf16x8*)(&xs[wave * 32 + rl][q * 8]);
        bf16x8 a1 = *(const bf16x8*)(&xs[wave * 32 + 16 + rl][q * 8]);
        acc0 = __builtin_amdgcn_mfma_f32_16x16x32_bf16(a0, bf, acc0, 0, 0, 0);
        acc1 = __builtin_amdgcn_mfma_f32_16x16x32_bf16(a1, bf, acc1, 0, 0, 0);
        __syncthreads();
    }

    // epilogue: C/D mapping col=lane&15, row=q*4+reg; fp32 out + fp32 bias
    const float bv = bias[j * 16 + rl];
    #pragma unroll
    for (int i2 = 0; i2 < 2; ++i2) {
        f32x4 a = i2 ? acc1 : acc0;
        const int base_m = m0 + wave * 32 + i2 * 16 + q * 4;
        #pragma unroll
        for (int rg = 0; rg < 4; ++rg) {
            out[(long long)(base_m + rg) * N_TOT + j * 16 + rl] = a[rg] + bv;
        }
    }
}

extern "C" void kernel_launch(void* const* d_in, const int* in_sizes, int n_in,
                              void* d_out, int out_size, void* d_ws, size_t ws_size,
                              hipStream_t stream) {
    const float* x    = (const float*)d_in[0];
    const float* w    = (const float*)d_in[1];
    const float* bias = (const float*)d_in[2];
    const unsigned char* mask = (const unsigned char*)d_in[3];
    float* out = (float*)d_out;

    bsl_detect<<<1, 256, 0, stream>>>(mask);

    dim3 grid(NB, M_TOT / BM);  // j fastest -> x-tile reuse in L2
    bsl_gemm<<<grid, 256, 0, stream>>>(x, w, bias, mask, out);
}